// Round 2
// baseline (9477.836 us; speedup 1.0000x reference)
//
#include <hip/hip_runtime.h>

#define T_LEN 256
#define B_SZ  64
#define H_SZ  1024
#define G4H   4096
#define HB    (B_SZ * H_SZ)              // 65536
#define WN    ((size_t)2 * G4H * H_SZ)   // one weight matrix set across layers: 8388608 elems

typedef __attribute__((ext_vector_type(8))) short short8;
typedef __attribute__((ext_vector_type(4))) float float4_;
typedef __attribute__((ext_vector_type(4))) unsigned short ushort4_;

__device__ __forceinline__ unsigned short bf16_rne(float x) {
  unsigned u = __builtin_bit_cast(unsigned, x);
  unsigned r = u + 0x7FFFu + ((u >> 16) & 1u);
  return (unsigned short)(r >> 16);
}
__device__ __forceinline__ float bf16_to_f32(unsigned short s) {
  unsigned u = ((unsigned)s) << 16;
  return __builtin_bit_cast(float, u);
}

// ---------- prep: fp32 weights -> split bf16 hi/lo planes ----------
__global__ __launch_bounds__(256)
void split_w(const float* __restrict__ src, unsigned short* __restrict__ hi,
             unsigned short* __restrict__ lo) {
  const size_t i = ((size_t)blockIdx.x * 256 + threadIdx.x) * 4;
  float4_ v = *(const float4_*)(src + i);
  ushort4_ h, l;
  #pragma unroll
  for (int j = 0; j < 4; ++j) {
    unsigned short hh = bf16_rne(v[j]);
    h[j] = hh;
    l[j] = bf16_rne(v[j] - bf16_to_f32(hh));
  }
  *(ushort4_*)(hi + i) = h;
  *(ushort4_*)(lo + i) = l;
}

// ---------- prep: bias presum ----------
__global__ __launch_bounds__(256)
void presum_bias(const float* __restrict__ bih, const float* __restrict__ bhh,
                 float* __restrict__ bsum) {
  const int i = blockIdx.x * 256 + threadIdx.x;  // grid covers exactly 2*4096
  bsum[i] = bih[i] + bhh[i];
}

// ---------- prep: h0 -> split ring (layer0 -> slot idx 1, layer1 -> slot idx 2) ----------
__global__ __launch_bounds__(256)
void init_h(const float* __restrict__ h0, unsigned short* __restrict__ rh,
            unsigned short* __restrict__ rl) {
  const int e0 = (blockIdx.x * 256 + threadIdx.x) * 4;
  #pragma unroll
  for (int j = 0; j < 4; ++j) {
    const int e = e0 + j;                 // [2][B][H] = 131072 elems
    const int l = e >> 16;
    const int rem = e & (HB - 1);
    const int slot = (l == 0) ? 1 : 2;    // layer*2 + initial slot
    const float v = h0[e];
    const unsigned short h = bf16_rne(v);
    rh[(size_t)slot * HB + rem] = h;
    rl[(size_t)slot * HB + rem] = bf16_rne(v - bf16_to_f32(h));
  }
}

// ---------- one pipelined step: layer0 does t=s, layer1 does t=s-1 ----------
// 256 WGs x 256 thr. wg>>7 = layer, wg&127 = cb (8 hcols = 32 gate cols = 2 MFMA n-tiles,
// gates permuted i/f/g/o into n-tiles). 4 waves split K (256 each), LDS reduce, fused
// elementwise, split-bf16 h write into 2-slot ring.
__global__ __launch_bounds__(256)
void lstm_step(int s,
               const float* __restrict__ x_in,
               const float* __restrict__ c0_in,
               const unsigned short* __restrict__ whi,   // [mat][L][4H][H] bf16-hi
               const unsigned short* __restrict__ wlo,
               const float* __restrict__ bsum,           // [L][4H]
               unsigned short* __restrict__ ring_hi,     // [2L * 2slots][B][H]
               unsigned short* __restrict__ ring_lo,
               float* __restrict__ c_ws,                 // [L][B][H]
               float* __restrict__ out)
{
  const int wg    = blockIdx.x;
  const int layer = wg >> 7;
  const int cb    = wg & 127;
  const bool active = (layer == 0) ? (s < T_LEN) : (s >= 1);
  if (!active) return;

  const int tid  = threadIdx.x;
  const int lane = tid & 63;
  const int wave = tid >> 6;
  const int nn   = lane & 15;
  const int quad = lane >> 4;

  __shared__ float lds[4][64][34];  // [wave][b][ncol], pad 34 -> conflict-free

  const int sl = (s - 1) & 1;  // slot written at step s-1 (init lands in slot 1 for s=0/1 first use)
  const unsigned short* hhi = ring_hi + (size_t)(layer * 2 + sl) * HB;
  const unsigned short* hlo = ring_lo + (size_t)(layer * 2 + sl) * HB;
  const float* xf = x_in + (size_t)s * HB;                    // layer0 input (fp32)
  const unsigned short* xhi = ring_hi + (size_t)sl * HB;      // layer1 input = layer0 h
  const unsigned short* xlo = ring_lo + (size_t)sl * HB;

  // gate rows for this lane's two n-tiles
  int growA[2];
  #pragma unroll
  for (int nt = 0; nt < 2; ++nt) {
    const int q = nt * 2 + (nn >> 3);
    growA[nt] = q * H_SZ + cb * 8 + (nn & 7);
  }

  float4_ acc[4][2];
  #pragma unroll
  for (int m = 0; m < 4; ++m)
    #pragma unroll
    for (int nt = 0; nt < 2; ++nt)
      acc[m][nt] = float4_{0.f, 0.f, 0.f, 0.f};

  #pragma unroll
  for (int kb = 0; kb < 8; ++kb) {
    const int k0 = wave * 256 + kb * 32 + quad * 8;

    short8 wv[2][2][2];  // [mat(ih,hh)][half(hi,lo)][ntile]
    #pragma unroll
    for (int mat = 0; mat < 2; ++mat) {
      const size_t mb = mat ? WN : (size_t)0;
      #pragma unroll
      for (int nt = 0; nt < 2; ++nt) {
        const size_t b0 = mb + ((size_t)layer * G4H + growA[nt]) * H_SZ + k0;
        wv[mat][0][nt] = *(const short8*)(whi + b0);
        wv[mat][1][nt] = *(const short8*)(wlo + b0);
      }
    }

    #pragma unroll
    for (int m = 0; m < 4; ++m) {
      const int row = m * 16 + nn;
      short8 ahi, alo;
      if (layer == 0) {
        const float* p = xf + (size_t)row * H_SZ + k0;
        #pragma unroll
        for (int j = 0; j < 8; ++j) {
          const float v = p[j];
          const unsigned short h = bf16_rne(v);
          ahi[j] = (short)h;
          alo[j] = (short)bf16_rne(v - bf16_to_f32(h));
        }
      } else {
        ahi = *(const short8*)(xhi + (size_t)row * H_SZ + k0);
        alo = *(const short8*)(xlo + (size_t)row * H_SZ + k0);
      }
      #pragma unroll
      for (int nt = 0; nt < 2; ++nt) {
        acc[m][nt] = __builtin_amdgcn_mfma_f32_16x16x32_bf16(ahi, wv[0][0][nt], acc[m][nt], 0, 0, 0);
        acc[m][nt] = __builtin_amdgcn_mfma_f32_16x16x32_bf16(alo, wv[0][0][nt], acc[m][nt], 0, 0, 0);
        acc[m][nt] = __builtin_amdgcn_mfma_f32_16x16x32_bf16(ahi, wv[0][1][nt], acc[m][nt], 0, 0, 0);
      }
      const short8 bhi = *(const short8*)(hhi + (size_t)row * H_SZ + k0);
      const short8 blo = *(const short8*)(hlo + (size_t)row * H_SZ + k0);
      #pragma unroll
      for (int nt = 0; nt < 2; ++nt) {
        acc[m][nt] = __builtin_amdgcn_mfma_f32_16x16x32_bf16(bhi, wv[1][0][nt], acc[m][nt], 0, 0, 0);
        acc[m][nt] = __builtin_amdgcn_mfma_f32_16x16x32_bf16(blo, wv[1][0][nt], acc[m][nt], 0, 0, 0);
        acc[m][nt] = __builtin_amdgcn_mfma_f32_16x16x32_bf16(bhi, wv[1][1][nt], acc[m][nt], 0, 0, 0);
      }
    }
  }

  // partials -> LDS. C/D layout: col = lane&15 (gate col), row = quad*4+reg (batch)
  #pragma unroll
  for (int m = 0; m < 4; ++m)
    #pragma unroll
    for (int nt = 0; nt < 2; ++nt)
      #pragma unroll
      for (int r = 0; r < 4; ++r)
        lds[wave][m * 16 + quad * 4 + r][nt * 16 + nn] = acc[m][nt][r];
  __syncthreads();

  // reduce over 4 K-slice waves + fused elementwise; 2 (b,hcol) pairs per thread
  #pragma unroll
  for (int pp = 0; pp < 2; ++pp) {
    const int p    = tid + pp * 256;
    const int b    = p >> 3;
    const int hc   = p & 7;
    const int hcol = cb * 8 + hc;
    float g[4];
    #pragma unroll
    for (int q = 0; q < 4; ++q) {
      const int ncol = q * 8 + hc;  // inverse of gate permutation: ncol -> gate q
      float sum = lds[0][b][ncol] + lds[1][b][ncol] + lds[2][b][ncol] + lds[3][b][ncol];
      sum += bsum[layer * G4H + q * H_SZ + hcol];
      g[q] = sum;
    }
    const size_t cidx  = (size_t)layer * HB + (size_t)b * H_SZ + hcol;
    const bool  cfirst = (layer == 0) ? (s == 0) : (s == 1);
    const float cprev  = cfirst ? c0_in[cidx] : c_ws[cidx];
    const float ig = 1.f / (1.f + __expf(-g[0]));
    const float fg = 1.f / (1.f + __expf(-g[1]));
    const float gg = tanhf(g[2]);
    const float og = 1.f / (1.f + __expf(-g[3]));
    const float cn = fg * cprev + ig * gg;
    const float hn = og * tanhf(cn);
    c_ws[cidx] = cn;
    const size_t ridx = (size_t)(layer * 2 + (s & 1)) * HB + (size_t)b * H_SZ + hcol;
    const unsigned short hh = bf16_rne(hn);
    ring_hi[ridx] = hh;
    ring_lo[ridx] = bf16_rne(hn - bf16_to_f32(hh));
    if (layer == 1 && s == T_LEN) out[(size_t)b * H_SZ + hcol] = hn;
  }
}

extern "C" void kernel_launch(void* const* d_in, const int* in_sizes, int n_in,
                              void* d_out, int out_size, void* d_ws, size_t ws_size,
                              hipStream_t stream) {
  (void)in_sizes; (void)n_in; (void)out_size; (void)ws_size;
  const float* x   = (const float*)d_in[0];
  const float* h0  = (const float*)d_in[1];
  const float* c0  = (const float*)d_in[2];
  const float* Wih = (const float*)d_in[3];
  const float* Whh = (const float*)d_in[4];
  const float* bih = (const float*)d_in[5];
  const float* bhh = (const float*)d_in[6];
  float* out = (float*)d_out;

  // workspace layout
  char* w = (char*)d_ws;
  unsigned short* whi     = (unsigned short*)w;                         // 2*WN shorts = 33.5 MB
  unsigned short* wlo     = (unsigned short*)(w + 2 * WN * 2);          // 33.5 MB
  unsigned short* ring_hi = (unsigned short*)(w + 4 * WN * 2);          // 4*HB*2 = 512 KB
  unsigned short* ring_lo = (unsigned short*)(w + 4 * WN * 2 + (size_t)4 * HB * 2);
  float*          c_ws    = (float*)(w + 4 * WN * 2 + (size_t)8 * HB * 2);   // 512 KB
  float*          bsum    = (float*)(w + 4 * WN * 2 + (size_t)8 * HB * 2 + (size_t)2 * HB * 4);

  // prep: split weights (once per call), bias presum, h0 ring init
  split_w<<<(int)(WN / 4 / 256), 256, 0, stream>>>(Wih, whi, wlo);
  split_w<<<(int)(WN / 4 / 256), 256, 0, stream>>>(Whh, whi + WN, wlo + WN);
  presum_bias<<<2 * G4H / 256, 256, 0, stream>>>(bih, bhh, bsum);
  init_h<<<2 * HB / 4 / 256, 256, 0, stream>>>(h0, ring_hi, ring_lo);

  // pipelined recurrence: dispatch boundary = grid-wide sync
  for (int s = 0; s <= T_LEN; ++s) {
    lstm_step<<<256, 256, 0, stream>>>(s, x, c0, whi, wlo, bsum,
                                       ring_hi, ring_lo, c_ws, out);
  }
}